// Round 10
// baseline (218.431 us; speedup 1.0000x reference)
//
#include <hip/hip_runtime.h>
#include <math.h>

// ---------------------------------------------------------------------------
// VMD, T = 2^20, K = 3.  u[k][t] = (f_hat[t] - lam[t]/2) * g_k(t), g_k real.
// fftshift folded into (-1)^n input modulation; ifftshift into (-1)^n output.
//
// Round-10:
//  - k_omega: 512 thr x 4 bins; DPP wave sums -> wsum[8][8] -> EVERY thread
//    re-reduces the 64 floats (LDS broadcast, fixed order, bitwise-identical
//    omega) -- the serial tid==0 stage (one LDS latency per leg) is gone.
//  - k_binpart fuses |fhat|^2 + transpose + per-32-col bin partials (DPP
//    32-lane sums) into one pass: m2 matrix never materialized, hist kernel
//    gone.  k_omega reduces 16 slab-partials/bin at load (deterministic).
//  - Hermitian packing: x real => conj(fhat[(N-t)%N]) = fhat[t], so
//    Re(ifft(u_k)) = ifft(fhat * Rsym_k) with Rsym_k(t) =
//    (R_k(fr_t)+R_k(fr_mirror))/2 computed analytically.  imf0+i*imf1 in one
//    complex iFFT, imf2 in the second: inverse traffic 180 -> 124 MB.
// ---------------------------------------------------------------------------

#define TN        (1 << 20)
#define NBINS     2048
#define PPB       512          // points per bin (TN/NBINS)
#define FALPHA    2000.0f
#define FTAU      1e-7f
#define FTOL      1e-6f
#define FEPS      1e-8f
#define FTWO_PI   6.28318530717958647692f
#define FINV_T    (1.0f / 1048576.0f)

__device__ __forceinline__ float2 cmulf(float2 a, float2 b) {
    return make_float2(a.x * b.x - a.y * b.y, a.x * b.y + a.y * b.x);
}
__device__ __forceinline__ float2 cisf(float a) {
    float s, c;
    __sincosf(a, &s, &c);
    return make_float2(c, s);
}

// g_k(fr) for K=3 with neighbor coupling (stale omega, like the reference)
__device__ __forceinline__ void g3f(float fr, float om0, float om1, float om2,
                                    float& g0, float& g1, float& g2) {
    const float tau2 = FTAU * FTAU;
    float d0 = fr - om0; d0 *= d0;
    float d1 = fr - om1; d1 *= d1;
    float d2 = fr - om2; d2 *= d2;
    g0 = __builtin_amdgcn_rcpf(1.0f + FALPHA * (d0 + d1 + tau2));
    g1 = __builtin_amdgcn_rcpf(1.0f + FALPHA * (d0 + d1 + d2 + tau2));
    g2 = __builtin_amdgcn_rcpf(1.0f + FALPHA * (d1 + d2 + tau2));
}

// wave64 sum via DPP: result valid in lane 63.
__device__ __forceinline__ float dpp_wave_sum(float x) {
    x += __int_as_float(__builtin_amdgcn_update_dpp(
             0, __float_as_int(x), 0x111, 0xf, 0xf, true));  // row_shr:1
    x += __int_as_float(__builtin_amdgcn_update_dpp(
             0, __float_as_int(x), 0x112, 0xf, 0xf, true));  // row_shr:2
    x += __int_as_float(__builtin_amdgcn_update_dpp(
             0, __float_as_int(x), 0x114, 0xf, 0xf, true));  // row_shr:4
    x += __int_as_float(__builtin_amdgcn_update_dpp(
             0, __float_as_int(x), 0x118, 0xf, 0xf, true));  // row_shr:8
    x += __int_as_float(__builtin_amdgcn_update_dpp(
             0, __float_as_int(x), 0x142, 0xf, 0xf, true));  // row_bcast:15
    x += __int_as_float(__builtin_amdgcn_update_dpp(
             0, __float_as_int(x), 0x143, 0xf, 0xf, true));  // row_bcast:31
    return x;
}
// 32-lane sums: after these 5 stages lane31 = sum(lanes 0..31),
// lane63 = sum(lanes 32..63).
__device__ __forceinline__ float dpp_sum32(float x) {
    x += __int_as_float(__builtin_amdgcn_update_dpp(
             0, __float_as_int(x), 0x111, 0xf, 0xf, true));
    x += __int_as_float(__builtin_amdgcn_update_dpp(
             0, __float_as_int(x), 0x112, 0xf, 0xf, true));
    x += __int_as_float(__builtin_amdgcn_update_dpp(
             0, __float_as_int(x), 0x114, 0xf, 0xf, true));
    x += __int_as_float(__builtin_amdgcn_update_dpp(
             0, __float_as_int(x), 0x118, 0xf, 0xf, true));
    x += __int_as_float(__builtin_amdgcn_update_dpp(
             0, __float_as_int(x), 0x142, 0xf, 0xf, true));  // row_bcast:15
    return x;
}

// ---------------------------------------------------------------------------
// fused |fhat|^2 + transpose + bin-partials.  True index t of scrambled (row
// qr, col qc) is qc*1024+qr.  Per block: 32 true-rows x one 32-col slab ->
// one partial (B, M1) per true-row.  d = ((col&511)-255.5)/T is the in-bin
// offset (bin = 2r + (col>=512)).  Layout: pB[bin*16 + (slab&15)].
// ---------------------------------------------------------------------------
__global__ __launch_bounds__(256)
void k_binpart(const float2* __restrict__ in, float* __restrict__ pB,
               float* __restrict__ pM) {
    __shared__ float tile[32][33];
    const int bx = blockIdx.x * 32, by = blockIdx.y * 32;
    const int tx = threadIdx.x, ty = threadIdx.y;
#pragma unroll
    for (int j = 0; j < 32; j += 8) {
        const float2 v = in[(size_t)(by + ty + j) * 1024 + bx + tx];
        tile[ty + j][tx] = v.x * v.x + v.y * v.y;
    }
    __syncthreads();
    const int slab = blockIdx.y;              // = by/32
    const int h = slab >> 4, sIdx = slab & 15;
    const float d = (((float)((by + tx) & 511)) - 255.5f) * FINV_T;
    const int lane = (tx + 32 * ty) & 63;
#pragma unroll
    for (int j = 0; j < 32; j += 8) {
        float s = tile[tx][ty + j];           // m2 at true-row bx+ty+j, col by+tx
        float m = s * d;
        s = dpp_sum32(s);
        m = dpp_sum32(m);
        if (lane == 31 || lane == 63) {
            const int r = bx + ty + j;
            const int bin = 2 * r + h;
            pB[bin * 16 + sIdx] = s;
            pM[bin * 16 + sIdx] = m;
        }
    }
}

// ---------------------------------------------------------------------------
// 49 omega updates over 2048 bins: 512 threads x 4 bins, no serial stage.
// Per bin & k: P_k = g^2*B + (g^2)'*M1,  W_k = c*P_k + g^2*M1,
// (g^2)' = -4*alpha*Dp_k*g^3.  sgs accumulates sum_i(gs_i - 1).
// ---------------------------------------------------------------------------
__global__ __launch_bounds__(512)
void k_omega(const float* __restrict__ pB, const float* __restrict__ pM,
             const float* __restrict__ omega0,
             float* __restrict__ oomf, float* __restrict__ sgsb) {
    const int tid = threadIdx.x;
    const int lane = tid & 63, wid = tid >> 6;   // 8 waves
    const float kA = -4.0f * FALPHA;

    float B[4], M[4], C[4], SG[4], gp[4];
#pragma unroll
    for (int i = 0; i < 4; ++i) {
        const int j = tid + 512 * i;
        float sb = 0.f, sm = 0.f;
#pragma unroll
        for (int s = 0; s < 16; ++s) {        // fixed order -> deterministic
            sb += pB[j * 16 + s];
            sm += pM[j * 16 + s];
        }
        B[i] = sb; M[i] = sm;
        C[i] = ((float)(j * PPB) + 255.5f) * FINV_T - 0.5f;
        SG[i] = 0.f; gp[i] = 0.f;
    }

    float om0 = 0.5f * omega0[0];
    float om1 = 0.5f * omega0[1];
    float om2 = 0.5f * omega0[2];
    float op0 = om0, op1 = om1, op2 = om2;
    float n0 = om0, n1 = om1, n2 = om2, stop = 0.f;

    __shared__ float wsum[8][8];
    bool fin = true;

    for (int n = 0; n < 49; ++n) {
        if (n > 0) {
            if (stop != 0.f) { fin = false; break; }
            op0 = om0; op1 = om1; op2 = om2;
            om0 = n0; om1 = n1; om2 = n2;
#pragma unroll
            for (int i = 0; i < 4; ++i) SG[i] += gp[i] - 1.0f;  // gs_{n-1}
        }
        const int check = (n > 0 && n % 10 == 0);

        float a[8];
#pragma unroll
        for (int v = 0; v < 8; ++v) a[v] = 0.f;

#pragma unroll
        for (int i = 0; i < 4; ++i) {
            const float c  = C[i];
            const float Bv = B[i];
            const float M1 = M[i];
            const float e0 = c - om0, e1 = c - om1, e2 = c - om2;
            float g0, g1, g2;
            g3f(c, om0, om1, om2, g0, g1, g2);
            const float gsq0 = g0 * g0, gsq1 = g1 * g1, gsq2 = g2 * g2;
            const float gc0 = gsq0 * g0, gc1 = gsq1 * g1, gc2 = gsq2 * g2;
            const float Dp0 = e0 + e1, Dp1 = e0 + e1 + e2, Dp2 = e1 + e2;
            const float P0 = gsq0 * Bv + kA * Dp0 * gc0 * M1;
            const float P1 = gsq1 * Bv + kA * Dp1 * gc1 * M1;
            const float P2 = gsq2 * Bv + kA * Dp2 * gc2 * M1;
            a[0] += P0; a[1] += P1; a[2] += P2;
            a[3] += c * P0 + gsq0 * M1;
            a[4] += c * P1 + gsq1 * M1;
            a[5] += c * P2 + gsq2 * M1;
            gp[i] = g0 + g1 + g2;
            if (check) {
                float h0, h1, h2;
                g3f(c, op0, op1, op2, h0, h1, h2);
                const float d0 = g0 - h0, d1 = g1 - h1, d2 = g2 - h2;
                a[6] += Bv * (d0 * d0 + d1 * d1 + d2 * d2);
                a[7] += Bv * (h0 * h0 + h1 * h1 + h2 * h2);
            }
        }
#pragma unroll
        for (int v = 0; v < 8; ++v) a[v] = dpp_wave_sum(a[v]);
        if (lane == 63) {
#pragma unroll
            for (int v = 0; v < 8; ++v) wsum[wid][v] = a[v];
        }
        __syncthreads();
        // every thread reduces (LDS broadcast, fixed order -> identical)
        float S[8];
#pragma unroll
        for (int v = 0; v < 8; ++v) {
            float s = 0.f;
#pragma unroll
            for (int w = 0; w < 8; ++w) s += wsum[w][v];
            S[v] = s;
        }
        n0 = S[3] / (S[0] + FEPS);
        n1 = S[4] / (S[1] + FEPS);
        n2 = S[5] / (S[2] + FEPS);
        if (check) {
            const float ud = S[6] / (S[7] + FEPS);
            const float od = (fabsf(n0 - n2) + fabsf(n1 - n0) +
                              fabsf(n2 - n1)) * (1.0f / 3.0f);
            stop = (ud < FTOL && od < FTOL) ? 1.f : 0.f;
        }
        __syncthreads();   // WAR: wsum rewritten next iteration
    }

    if (fin) {             // completed: omega entering iter 49, sgs 0..48
#pragma unroll
        for (int i = 0; i < 4; ++i) SG[i] += gp[i] - 1.0f;
        om0 = n0; om1 = n1; om2 = n2;
    }
#pragma unroll
    for (int i = 0; i < 4; ++i) sgsb[tid + 512 * i] = SG[i];
    if (tid == 0) { oomf[0] = om0; oomf[1] = om1; oomf[2] = om2; }
}

// ---------------------------------------------------------------------------
// 1024-point Stockham radix-4 stages in LDS (caller loads bufA, then syncs)
// ---------------------------------------------------------------------------
__device__ __forceinline__ float2* fft1024_stages(float2* bufA, float2* bufB,
                                                  int t, float dir) {
    float2* src = bufA;
    float2* dst = bufB;
    int Ns = 1;
#pragma unroll
    for (int s = 0; s < 5; ++s) {
        const int jm = t & (Ns - 1);
        float2 v0 = src[t], v1 = src[t + 256], v2 = src[t + 512], v3 = src[t + 768];
        const float a = dir * (FTWO_PI * 0.25f) * ((float)jm / (float)Ns);
        float2 w1 = cisf(a);
        float2 w2 = cmulf(w1, w1);
        float2 w3 = cmulf(w2, w1);
        v1 = cmulf(v1, w1); v2 = cmulf(v2, w2); v3 = cmulf(v3, w3);
        float2 s0 = make_float2(v0.x + v2.x, v0.y + v2.y);
        float2 s1 = make_float2(v0.x - v2.x, v0.y - v2.y);
        float2 s2 = make_float2(v1.x + v3.x, v1.y + v3.y);
        float2 s3 = make_float2(v1.x - v3.x, v1.y - v3.y);
        float2 s3i = make_float2(-dir * s3.y, dir * s3.x);  // dir*i * s3
        const int base = ((t - jm) << 2) + jm;
        dst[base]          = make_float2(s0.x + s2.x, s0.y + s2.y);
        dst[base + Ns]     = make_float2(s1.x + s3i.x, s1.y + s3i.y);
        dst[base + 2 * Ns] = make_float2(s0.x - s2.x, s0.y - s2.y);
        dst[base + 3 * Ns] = make_float2(s1.x - s3i.x, s1.y - s3i.y);
        __syncthreads();
        float2* tmp = src; src = dst; dst = tmp;
        Ns <<= 2;
    }
    return src;
}

// generic row FFT: dir=-1 fwd / +1 inv; do_tw: * e^{dir*2pi*i*row*col/2^20}
__global__ __launch_bounds__(256)
void k_fft1024(const float2* __restrict__ in, float2* __restrict__ out,
               float dir, int do_tw) {
    __shared__ float2 bufA[1024];
    __shared__ float2 bufB[1024];
    const int row  = blockIdx.x;
    const int rowm = row & 1023;
    const float2* __restrict__ rin  = in  + (size_t)row * 1024;
    float2* __restrict__ rout = out + (size_t)row * 1024;
    const int t = threadIdx.x;
#pragma unroll
    for (int r = 0; r < 4; ++r) bufA[t + 256 * r] = rin[t + 256 * r];
    __syncthreads();
    float2* src = fft1024_stages(bufA, bufB, t, dir);
#pragma unroll
    for (int r = 0; r < 4; ++r) {
        const int c = t + 256 * r;
        float2 xv = src[c];
        if (do_tw) {
            const unsigned p = ((unsigned)rowm * (unsigned)c) & 1048575u;
            xv = cmulf(xv, cisf(dir * (FTWO_PI * FINV_T) * (float)p));
        }
        rout[c] = xv;
    }
}

// first inverse-FFT pass, Hermitian-packed filters fused into the load:
// z=0: Z = fhat*(Rsym_0 + i*Rsym_1)  (ifft -> imf0 + i*imf1, both real)
// z=1: Z = fhat*Rsym_2               (ifft real part -> imf2)
// Rsym_k(t) = (g_k(fr)*sc(t) + g_k(fr_m)*sc(tm))/2, tm = (N-t)&(N-1).
__global__ __launch_bounds__(256)
void k_fftu(const float2* __restrict__ fhat, const float* __restrict__ sgsb,
            const float* __restrict__ oomf,
            float2* __restrict__ out, int zbase) {
    __shared__ float2 bufA[1024];
    __shared__ float2 bufB[1024];
    const int row = blockIdx.x & 1023;
    const int zi  = blockIdx.x >> 10;
    const int z   = zi + zbase;
    const float om0 = oomf[0], om1 = oomf[1], om2 = oomf[2];
    const float2* __restrict__ frow = fhat + (size_t)row * 1024;
    const int t = threadIdx.x;
#pragma unroll
    for (int r = 0; r < 4; ++r) {
        const int c = t + 256 * r;
        const float2 f = frow[c];
        const int tt = (c << 10) | row;
        const float fr = (float)tt * FINV_T - 0.5f;
        const float sc = 1.0f - 0.5f * FTAU * sgsb[tt >> 9];
        float g0, g1, g2;
        g3f(fr, om0, om1, om2, g0, g1, g2);
        const int tm = (TN - tt) & (TN - 1);
        const float frm = (float)tm * FINV_T - 0.5f;
        const float scm = 1.0f - 0.5f * FTAU * sgsb[tm >> 9];
        float h0, h1, h2;
        g3f(frm, om0, om1, om2, h0, h1, h2);
        float A, Bi;
        if (z == 0) {
            A  = 0.5f * (g0 * sc + h0 * scm);
            Bi = 0.5f * (g1 * sc + h1 * scm);
        } else {
            A  = 0.5f * (g2 * sc + h2 * scm);
            Bi = 0.f;
        }
        bufA[c] = cmulf(f, make_float2(A, Bi));
    }
    __syncthreads();
    float2* src = fft1024_stages(bufA, bufB, t, 1.0f);
    float2* __restrict__ rout = out + (size_t)zi * TN + (size_t)row * 1024;
#pragma unroll
    for (int r = 0; r < 4; ++r) {
        const int c = t + 256 * r;
        const unsigned p = ((unsigned)row * (unsigned)c) & 1048575u;
        rout[c] = cmulf(src[c], cisf((FTWO_PI * FINV_T) * (float)p));
    }
}

// ---------------------------------------------------------------------------
// transposes (32x32 LDS tiles, block (32,8)); grid z = batch
// ---------------------------------------------------------------------------
__global__ __launch_bounds__(256)
void k_tr_c2c(const float2* __restrict__ in, float2* __restrict__ out) {
    __shared__ float2 tile[32][33];
    const size_t zo = (size_t)blockIdx.z * TN;
    const int bx = blockIdx.x * 32, by = blockIdx.y * 32;
    const int tx = threadIdx.x, ty = threadIdx.y;
#pragma unroll
    for (int j = 0; j < 32; j += 8)
        tile[ty + j][tx] = in[zo + (size_t)(by + ty + j) * 1024 + bx + tx];
    __syncthreads();
#pragma unroll
    for (int j = 0; j < 32; j += 8)
        out[zo + (size_t)(bx + ty + j) * 1024 + by + tx] = tile[tx][ty + j];
}

// forward input: y = (-1)^n * x, transposed, real -> complex
__global__ __launch_bounds__(256)
void k_tr_fwd_in(const float* __restrict__ in, float2* __restrict__ out) {
    __shared__ float tile[32][33];
    const int bx = blockIdx.x * 32, by = blockIdx.y * 32;
    const int tx = threadIdx.x, ty = threadIdx.y;
#pragma unroll
    for (int j = 0; j < 32; j += 8)
        tile[ty + j][tx] = in[(size_t)(by + ty + j) * 1024 + bx + tx];
    __syncthreads();
#pragma unroll
    for (int j = 0; j < 32; j += 8) {
        const int r = bx + ty + j;
        float v = tile[tx][ty + j];
        v = (r & 1) ? -v : v;
        out[(size_t)r * 1024 + by + tx] = make_float2(v, 0.0f);
    }
}

// inverse output: imf = (-1)^n * (1/N) * (re, and im if packed), transposed.
// z==0 block writes imf0 (re) and imf1 (im); z==1 writes imf2 (re).
__global__ __launch_bounds__(256)
void k_tr_out(const float2* __restrict__ in, float* __restrict__ out,
              int zbase) {
    __shared__ float2 tile[32][33];
    const int z = blockIdx.z + zbase;
    const size_t zo = (size_t)blockIdx.z * TN;
    const int bx = blockIdx.x * 32, by = blockIdx.y * 32;
    const int tx = threadIdx.x, ty = threadIdx.y;
#pragma unroll
    for (int j = 0; j < 32; j += 8)
        tile[ty + j][tx] = in[zo + (size_t)(by + ty + j) * 1024 + bx + tx];
    __syncthreads();
    const int c = by + tx;
    const float sgn = (c & 1) ? -FINV_T : FINV_T;
#pragma unroll
    for (int j = 0; j < 32; j += 8) {
        const int r = bx + ty + j;
        const float2 v = tile[tx][ty + j];
        const size_t idx = (size_t)r * 1024 + c;
        if (z == 0) {
            out[idx]             = v.x * sgn;   // imf0
            out[(size_t)TN + idx] = v.y * sgn;  // imf1
        } else {
            out[2 * (size_t)TN + idx] = v.x * sgn;  // imf2
        }
    }
}

// ---------------------------------------------------------------------------
extern "C" void kernel_launch(void* const* d_in, const int* in_sizes, int n_in,
                              void* d_out, int out_size, void* d_ws, size_t ws_size,
                              hipStream_t stream) {
    (void)in_sizes; (void)n_in; (void)out_size;
    const float* x      = (const float*)d_in[0];
    const float* omega0 = (const float*)d_in[1];
    float* outp = (float*)d_out;
    char* ws = (char*)d_ws;

    const size_t MB = (size_t)1 << 20;
    const size_t KB = (size_t)1 << 10;
    float2* fhat = (float2*)(ws);                      // 8 MB (scrambled)
    float*  pB   = (float*)(ws + 8 * MB);              // 128 KB
    float*  pM   = (float*)(ws + 8 * MB + 128 * KB);   // 128 KB
    float*  sgsb = (float*)(ws + 8 * MB + 256 * KB);   // 8 KB
    float*  oomf = (float*)(ws + 8 * MB + 264 * KB);   // 3 floats
    const bool batch2 = ws_size >= 42 * MB;
    float2* sA = (float2*)(ws + 9 * MB);               // 16 or 8 MB
    float2* sB = batch2 ? (float2*)(ws + 25 * MB)
                        : (float2*)(ws + 17 * MB);

    dim3 tb(32, 8);
    dim3 tg(32, 32);

    // forward FFT of (-1)^n*x -> fhat in scrambled order (4 passes)
    k_tr_fwd_in<<<tg, tb, 0, stream>>>(x, sA);
    k_fft1024<<<1024, 256, 0, stream>>>(sA, sB, -1.0f, 1);
    k_tr_c2c<<<tg, tb, 0, stream>>>(sB, sA);
    k_fft1024<<<1024, 256, 0, stream>>>(sA, fhat, -1.0f, 0);

    // fused spectrum compression: fhat -> per-slab bin partials
    k_binpart<<<tg, tb, 0, stream>>>(fhat, pB, pM);

    // 49 omega updates in one small block
    k_omega<<<1, 512, 0, stream>>>(pB, pM, omega0, oomf, sgsb);

    // Hermitian-packed inverse: 2 complex iFFTs -> 3 real IMFs
    if (batch2) {
        k_fftu<<<2048, 256, 0, stream>>>(fhat, sgsb, oomf, sB, 0);
        k_tr_c2c<<<dim3(32, 32, 2), tb, 0, stream>>>(sB, sA);
        k_fft1024<<<2048, 256, 0, stream>>>(sA, sB, 1.0f, 0);
        k_tr_out<<<dim3(32, 32, 2), tb, 0, stream>>>(sB, outp, 0);
    } else {
        for (int z = 0; z < 2; ++z) {
            k_fftu<<<1024, 256, 0, stream>>>(fhat, sgsb, oomf, sB, z);
            k_tr_c2c<<<tg, tb, 0, stream>>>(sB, sA);
            k_fft1024<<<1024, 256, 0, stream>>>(sA, sB, 1.0f, 0);
            k_tr_out<<<dim3(32, 32, 1), tb, 0, stream>>>(sB, outp, z);
        }
    }
}

// Round 11
// 194.689 us; speedup vs baseline: 1.1219x; 1.1219x over previous
//
#include <hip/hip_runtime.h>
#include <math.h>

// ---------------------------------------------------------------------------
// VMD, T = 2^20, K = 3.  u[k][t] = (f_hat[t] - lam[t]/2) * g_k(t), g_k real.
// fftshift folded into (-1)^n input modulation; ifftshift into (-1)^n output.
//
// Round-11: round-10's every-thread LDS reduce regressed (512 LDS broadcast
// transactions/iter on one CU's LDS pipe).  k_omega back to 256 thr x 8 bins
// (1 wave/SIMD) with a wave-local tail: lane63 stores 2 float4s -> ONE
// barrier -> every lane reads wsum[w][lane&7] (4 broadcast reads) ->
// v_readlane x8 -> uniform omega via rcp.  6 LDS transactions + 1 barrier
// per iteration; wsum parity-double-buffered (no 2nd barrier, WAR-safe by
// barrier induction).  Everything else unchanged from round 10 (fused
// binpart, Hermitian-packed 2-iFFT inverse).
// ---------------------------------------------------------------------------

#define TN        (1 << 20)
#define NBINS     2048
#define PPB       512          // points per bin (TN/NBINS)
#define FALPHA    2000.0f
#define FTAU      1e-7f
#define FTOL      1e-6f
#define FEPS      1e-8f
#define FTWO_PI   6.28318530717958647692f
#define FINV_T    (1.0f / 1048576.0f)

__device__ __forceinline__ float2 cmulf(float2 a, float2 b) {
    return make_float2(a.x * b.x - a.y * b.y, a.x * b.y + a.y * b.x);
}
__device__ __forceinline__ float2 cisf(float a) {
    float s, c;
    __sincosf(a, &s, &c);
    return make_float2(c, s);
}
__device__ __forceinline__ float rlanef(float v, int l) {
    return __int_as_float(__builtin_amdgcn_readlane(__float_as_int(v), l));
}

// g_k(fr) for K=3 with neighbor coupling (stale omega, like the reference)
__device__ __forceinline__ void g3f(float fr, float om0, float om1, float om2,
                                    float& g0, float& g1, float& g2) {
    const float tau2 = FTAU * FTAU;
    float d0 = fr - om0; d0 *= d0;
    float d1 = fr - om1; d1 *= d1;
    float d2 = fr - om2; d2 *= d2;
    g0 = __builtin_amdgcn_rcpf(1.0f + FALPHA * (d0 + d1 + tau2));
    g1 = __builtin_amdgcn_rcpf(1.0f + FALPHA * (d0 + d1 + d2 + tau2));
    g2 = __builtin_amdgcn_rcpf(1.0f + FALPHA * (d1 + d2 + tau2));
}

// wave64 sum via DPP: result valid in lane 63.
__device__ __forceinline__ float dpp_wave_sum(float x) {
    x += __int_as_float(__builtin_amdgcn_update_dpp(
             0, __float_as_int(x), 0x111, 0xf, 0xf, true));  // row_shr:1
    x += __int_as_float(__builtin_amdgcn_update_dpp(
             0, __float_as_int(x), 0x112, 0xf, 0xf, true));  // row_shr:2
    x += __int_as_float(__builtin_amdgcn_update_dpp(
             0, __float_as_int(x), 0x114, 0xf, 0xf, true));  // row_shr:4
    x += __int_as_float(__builtin_amdgcn_update_dpp(
             0, __float_as_int(x), 0x118, 0xf, 0xf, true));  // row_shr:8
    x += __int_as_float(__builtin_amdgcn_update_dpp(
             0, __float_as_int(x), 0x142, 0xf, 0xf, true));  // row_bcast:15
    x += __int_as_float(__builtin_amdgcn_update_dpp(
             0, __float_as_int(x), 0x143, 0xf, 0xf, true));  // row_bcast:31
    return x;
}
// 32-lane sums: lane31 = sum(0..31), lane63 = sum(32..63).
__device__ __forceinline__ float dpp_sum32(float x) {
    x += __int_as_float(__builtin_amdgcn_update_dpp(
             0, __float_as_int(x), 0x111, 0xf, 0xf, true));
    x += __int_as_float(__builtin_amdgcn_update_dpp(
             0, __float_as_int(x), 0x112, 0xf, 0xf, true));
    x += __int_as_float(__builtin_amdgcn_update_dpp(
             0, __float_as_int(x), 0x114, 0xf, 0xf, true));
    x += __int_as_float(__builtin_amdgcn_update_dpp(
             0, __float_as_int(x), 0x118, 0xf, 0xf, true));
    x += __int_as_float(__builtin_amdgcn_update_dpp(
             0, __float_as_int(x), 0x142, 0xf, 0xf, true));  // row_bcast:15
    return x;
}

// ---------------------------------------------------------------------------
// fused |fhat|^2 + transpose + bin-partials.  True index t of scrambled (row
// qr, col qc) is qc*1024+qr.  Per block: 32 true-rows x one 32-col slab ->
// one partial (B, M1) per true-row.  Layout: pB[bin*16 + (slab&15)].
// ---------------------------------------------------------------------------
__global__ __launch_bounds__(256)
void k_binpart(const float2* __restrict__ in, float* __restrict__ pB,
               float* __restrict__ pM) {
    __shared__ float tile[32][33];
    const int bx = blockIdx.x * 32, by = blockIdx.y * 32;
    const int tx = threadIdx.x, ty = threadIdx.y;
#pragma unroll
    for (int j = 0; j < 32; j += 8) {
        const float2 v = in[(size_t)(by + ty + j) * 1024 + bx + tx];
        tile[ty + j][tx] = v.x * v.x + v.y * v.y;
    }
    __syncthreads();
    const int slab = blockIdx.y;              // = by/32
    const int h = slab >> 4, sIdx = slab & 15;
    const float d = (((float)((by + tx) & 511)) - 255.5f) * FINV_T;
    const int lane = (tx + 32 * ty) & 63;
#pragma unroll
    for (int j = 0; j < 32; j += 8) {
        float s = tile[tx][ty + j];           // m2 at true-row bx+ty+j, col by+tx
        float m = s * d;
        s = dpp_sum32(s);
        m = dpp_sum32(m);
        if (lane == 31 || lane == 63) {
            const int r = bx + ty + j;
            const int bin = 2 * r + h;
            pB[bin * 16 + sIdx] = s;
            pM[bin * 16 + sIdx] = m;
        }
    }
}

// ---------------------------------------------------------------------------
// 49 omega updates over 2048 bins: 256 threads x 8 bins, wave-local tail.
// Per bin & k: P_k = g^2*B + (g^2)'*M1,  W_k = c*P_k + g^2*M1,
// (g^2)' = -4*alpha*Dp_k*g^3.  sgs accumulates sum_i(gs_i - 1).
// ---------------------------------------------------------------------------
__global__ __launch_bounds__(256)
void k_omega(const float* __restrict__ pB, const float* __restrict__ pM,
             const float* __restrict__ omega0,
             float* __restrict__ oomf, float* __restrict__ sgsb) {
    const int tid = threadIdx.x;
    const int lane = tid & 63, wid = tid >> 6;   // 4 waves
    const float kA = -4.0f * FALPHA;

    float B[8], M[8], C[8], SG[8], gp[8];
#pragma unroll
    for (int i = 0; i < 8; ++i) {
        const int j = tid + 256 * i;
        float sb = 0.f, sm = 0.f;
#pragma unroll
        for (int s = 0; s < 16; ++s) {        // fixed order -> deterministic
            sb += pB[j * 16 + s];
            sm += pM[j * 16 + s];
        }
        B[i] = sb; M[i] = sm;
        C[i] = ((float)(j * PPB) + 255.5f) * FINV_T - 0.5f;
        SG[i] = 0.f; gp[i] = 0.f;
    }

    float om0 = 0.5f * omega0[0];
    float om1 = 0.5f * omega0[1];
    float om2 = 0.5f * omega0[2];
    float op0 = om0, op1 = om1, op2 = om2;
    float n0 = om0, n1 = om1, n2 = om2;
    float stop = 0.f;

    __shared__ float wsum[2][4][8];           // parity double-buffer
    bool fin = true;

    for (int n = 0; n < 49; ++n) {
        if (n > 0) {
            if (stop != 0.f) { fin = false; break; }
            op0 = om0; op1 = om1; op2 = om2;
            om0 = n0; om1 = n1; om2 = n2;
#pragma unroll
            for (int i = 0; i < 8; ++i) SG[i] += gp[i] - 1.0f;  // gs_{n-1}
        }
        const int check = (n > 0 && n % 10 == 0);

        float a[8];
#pragma unroll
        for (int v = 0; v < 8; ++v) a[v] = 0.f;

#pragma unroll
        for (int i = 0; i < 8; ++i) {
            const float c  = C[i];
            const float Bv = B[i];
            const float M1 = M[i];
            const float e0 = c - om0, e1 = c - om1, e2 = c - om2;
            float g0, g1, g2;
            g3f(c, om0, om1, om2, g0, g1, g2);
            const float gsq0 = g0 * g0, gsq1 = g1 * g1, gsq2 = g2 * g2;
            const float gc0 = gsq0 * g0, gc1 = gsq1 * g1, gc2 = gsq2 * g2;
            const float Dp0 = e0 + e1, Dp1 = e0 + e1 + e2, Dp2 = e1 + e2;
            const float P0 = gsq0 * Bv + kA * Dp0 * gc0 * M1;
            const float P1 = gsq1 * Bv + kA * Dp1 * gc1 * M1;
            const float P2 = gsq2 * Bv + kA * Dp2 * gc2 * M1;
            a[0] += P0; a[1] += P1; a[2] += P2;
            a[3] += c * P0 + gsq0 * M1;
            a[4] += c * P1 + gsq1 * M1;
            a[5] += c * P2 + gsq2 * M1;
            gp[i] = g0 + g1 + g2;
            if (check) {
                float h0, h1, h2;
                g3f(c, op0, op1, op2, h0, h1, h2);
                const float d0 = g0 - h0, d1 = g1 - h1, d2 = g2 - h2;
                a[6] += Bv * (d0 * d0 + d1 * d1 + d2 * d2);
                a[7] += Bv * (h0 * h0 + h1 * h1 + h2 * h2);
            }
        }
        // wave sums land in lane 63; 2 float4 LDS stores from that lane
#pragma unroll
        for (int v = 0; v < 8; ++v) a[v] = dpp_wave_sum(a[v]);
        if (lane == 63) {
            *(float4*)&wsum[n & 1][wid][0] = make_float4(a[0], a[1], a[2], a[3]);
            *(float4*)&wsum[n & 1][wid][4] = make_float4(a[4], a[5], a[6], a[7]);
        }
        __syncthreads();                       // the ONLY barrier per iter
        // every lane: 4 broadcast reads -> lane l holds S[l&7]; readlane ->
        // uniform totals, identical in every wave (same data, same order).
        const float r = wsum[n & 1][0][lane & 7] + wsum[n & 1][1][lane & 7] +
                        wsum[n & 1][2][lane & 7] + wsum[n & 1][3][lane & 7];
        const float S0 = rlanef(r, 0), S1 = rlanef(r, 1), S2 = rlanef(r, 2);
        const float S3 = rlanef(r, 3), S4 = rlanef(r, 4), S5 = rlanef(r, 5);
        n0 = S3 * __builtin_amdgcn_rcpf(S0 + FEPS);
        n1 = S4 * __builtin_amdgcn_rcpf(S1 + FEPS);
        n2 = S5 * __builtin_amdgcn_rcpf(S2 + FEPS);
        if (check) {
            const float S6 = rlanef(r, 6), S7 = rlanef(r, 7);
            const float ud = S6 * __builtin_amdgcn_rcpf(S7 + FEPS);
            const float od = (fabsf(n0 - n2) + fabsf(n1 - n0) +
                              fabsf(n2 - n1)) * (1.0f / 3.0f);
            stop = (ud < FTOL && od < FTOL) ? 1.f : 0.f;
        }
    }

    if (fin) {             // completed: omega entering iter 49, sgs 0..48
#pragma unroll
        for (int i = 0; i < 8; ++i) SG[i] += gp[i] - 1.0f;
        om0 = n0; om1 = n1; om2 = n2;
    }
#pragma unroll
    for (int i = 0; i < 8; ++i) sgsb[tid + 256 * i] = SG[i];
    if (tid == 0) { oomf[0] = om0; oomf[1] = om1; oomf[2] = om2; }
}

// ---------------------------------------------------------------------------
// 1024-point Stockham radix-4 stages in LDS (caller loads bufA, then syncs)
// ---------------------------------------------------------------------------
__device__ __forceinline__ float2* fft1024_stages(float2* bufA, float2* bufB,
                                                  int t, float dir) {
    float2* src = bufA;
    float2* dst = bufB;
    int Ns = 1;
#pragma unroll
    for (int s = 0; s < 5; ++s) {
        const int jm = t & (Ns - 1);
        float2 v0 = src[t], v1 = src[t + 256], v2 = src[t + 512], v3 = src[t + 768];
        const float a = dir * (FTWO_PI * 0.25f) * ((float)jm / (float)Ns);
        float2 w1 = cisf(a);
        float2 w2 = cmulf(w1, w1);
        float2 w3 = cmulf(w2, w1);
        v1 = cmulf(v1, w1); v2 = cmulf(v2, w2); v3 = cmulf(v3, w3);
        float2 s0 = make_float2(v0.x + v2.x, v0.y + v2.y);
        float2 s1 = make_float2(v0.x - v2.x, v0.y - v2.y);
        float2 s2 = make_float2(v1.x + v3.x, v1.y + v3.y);
        float2 s3 = make_float2(v1.x - v3.x, v1.y - v3.y);
        float2 s3i = make_float2(-dir * s3.y, dir * s3.x);  // dir*i * s3
        const int base = ((t - jm) << 2) + jm;
        dst[base]          = make_float2(s0.x + s2.x, s0.y + s2.y);
        dst[base + Ns]     = make_float2(s1.x + s3i.x, s1.y + s3i.y);
        dst[base + 2 * Ns] = make_float2(s0.x - s2.x, s0.y - s2.y);
        dst[base + 3 * Ns] = make_float2(s1.x - s3i.x, s1.y - s3i.y);
        __syncthreads();
        float2* tmp = src; src = dst; dst = tmp;
        Ns <<= 2;
    }
    return src;
}

// generic row FFT: dir=-1 fwd / +1 inv; do_tw: * e^{dir*2pi*i*row*col/2^20}
__global__ __launch_bounds__(256)
void k_fft1024(const float2* __restrict__ in, float2* __restrict__ out,
               float dir, int do_tw) {
    __shared__ float2 bufA[1024];
    __shared__ float2 bufB[1024];
    const int row  = blockIdx.x;
    const int rowm = row & 1023;
    const float2* __restrict__ rin  = in  + (size_t)row * 1024;
    float2* __restrict__ rout = out + (size_t)row * 1024;
    const int t = threadIdx.x;
#pragma unroll
    for (int r = 0; r < 4; ++r) bufA[t + 256 * r] = rin[t + 256 * r];
    __syncthreads();
    float2* src = fft1024_stages(bufA, bufB, t, dir);
#pragma unroll
    for (int r = 0; r < 4; ++r) {
        const int c = t + 256 * r;
        float2 xv = src[c];
        if (do_tw) {
            const unsigned p = ((unsigned)rowm * (unsigned)c) & 1048575u;
            xv = cmulf(xv, cisf(dir * (FTWO_PI * FINV_T) * (float)p));
        }
        rout[c] = xv;
    }
}

// first inverse-FFT pass, Hermitian-packed filters fused into the load:
// z=0: Z = fhat*(Rsym_0 + i*Rsym_1)  (ifft -> imf0 + i*imf1, both real)
// z=1: Z = fhat*Rsym_2               (ifft real part -> imf2)
// Rsym_k(t) = (g_k(fr)*sc(t) + g_k(fr_m)*sc(tm))/2, tm = (N-t)&(N-1).
__global__ __launch_bounds__(256)
void k_fftu(const float2* __restrict__ fhat, const float* __restrict__ sgsb,
            const float* __restrict__ oomf,
            float2* __restrict__ out, int zbase) {
    __shared__ float2 bufA[1024];
    __shared__ float2 bufB[1024];
    const int row = blockIdx.x & 1023;
    const int zi  = blockIdx.x >> 10;
    const int z   = zi + zbase;
    const float om0 = oomf[0], om1 = oomf[1], om2 = oomf[2];
    const float2* __restrict__ frow = fhat + (size_t)row * 1024;
    const int t = threadIdx.x;
#pragma unroll
    for (int r = 0; r < 4; ++r) {
        const int c = t + 256 * r;
        const float2 f = frow[c];
        const int tt = (c << 10) | row;
        const float fr = (float)tt * FINV_T - 0.5f;
        const float sc = 1.0f - 0.5f * FTAU * sgsb[tt >> 9];
        float g0, g1, g2;
        g3f(fr, om0, om1, om2, g0, g1, g2);
        const int tm = (TN - tt) & (TN - 1);
        const float frm = (float)tm * FINV_T - 0.5f;
        const float scm = 1.0f - 0.5f * FTAU * sgsb[tm >> 9];
        float h0, h1, h2;
        g3f(frm, om0, om1, om2, h0, h1, h2);
        float A, Bi;
        if (z == 0) {
            A  = 0.5f * (g0 * sc + h0 * scm);
            Bi = 0.5f * (g1 * sc + h1 * scm);
        } else {
            A  = 0.5f * (g2 * sc + h2 * scm);
            Bi = 0.f;
        }
        bufA[c] = cmulf(f, make_float2(A, Bi));
    }
    __syncthreads();
    float2* src = fft1024_stages(bufA, bufB, t, 1.0f);
    float2* __restrict__ rout = out + (size_t)zi * TN + (size_t)row * 1024;
#pragma unroll
    for (int r = 0; r < 4; ++r) {
        const int c = t + 256 * r;
        const unsigned p = ((unsigned)row * (unsigned)c) & 1048575u;
        rout[c] = cmulf(src[c], cisf((FTWO_PI * FINV_T) * (float)p));
    }
}

// ---------------------------------------------------------------------------
// transposes (32x32 LDS tiles, block (32,8)); grid z = batch
// ---------------------------------------------------------------------------
__global__ __launch_bounds__(256)
void k_tr_c2c(const float2* __restrict__ in, float2* __restrict__ out) {
    __shared__ float2 tile[32][33];
    const size_t zo = (size_t)blockIdx.z * TN;
    const int bx = blockIdx.x * 32, by = blockIdx.y * 32;
    const int tx = threadIdx.x, ty = threadIdx.y;
#pragma unroll
    for (int j = 0; j < 32; j += 8)
        tile[ty + j][tx] = in[zo + (size_t)(by + ty + j) * 1024 + bx + tx];
    __syncthreads();
#pragma unroll
    for (int j = 0; j < 32; j += 8)
        out[zo + (size_t)(bx + ty + j) * 1024 + by + tx] = tile[tx][ty + j];
}

// forward input: y = (-1)^n * x, transposed, real -> complex
__global__ __launch_bounds__(256)
void k_tr_fwd_in(const float* __restrict__ in, float2* __restrict__ out) {
    __shared__ float tile[32][33];
    const int bx = blockIdx.x * 32, by = blockIdx.y * 32;
    const int tx = threadIdx.x, ty = threadIdx.y;
#pragma unroll
    for (int j = 0; j < 32; j += 8)
        tile[ty + j][tx] = in[(size_t)(by + ty + j) * 1024 + bx + tx];
    __syncthreads();
#pragma unroll
    for (int j = 0; j < 32; j += 8) {
        const int r = bx + ty + j;
        float v = tile[tx][ty + j];
        v = (r & 1) ? -v : v;
        out[(size_t)r * 1024 + by + tx] = make_float2(v, 0.0f);
    }
}

// inverse output: imf = (-1)^n * (1/N) * (re, and im if packed), transposed.
// z==0 block writes imf0 (re) and imf1 (im); z==1 writes imf2 (re).
__global__ __launch_bounds__(256)
void k_tr_out(const float2* __restrict__ in, float* __restrict__ out,
              int zbase) {
    __shared__ float2 tile[32][33];
    const int z = blockIdx.z + zbase;
    const size_t zo = (size_t)blockIdx.z * TN;
    const int bx = blockIdx.x * 32, by = blockIdx.y * 32;
    const int tx = threadIdx.x, ty = threadIdx.y;
#pragma unroll
    for (int j = 0; j < 32; j += 8)
        tile[ty + j][tx] = in[zo + (size_t)(by + ty + j) * 1024 + bx + tx];
    __syncthreads();
    const int c = by + tx;
    const float sgn = (c & 1) ? -FINV_T : FINV_T;
#pragma unroll
    for (int j = 0; j < 32; j += 8) {
        const int r = bx + ty + j;
        const float2 v = tile[tx][ty + j];
        const size_t idx = (size_t)r * 1024 + c;
        if (z == 0) {
            out[idx]              = v.x * sgn;   // imf0
            out[(size_t)TN + idx] = v.y * sgn;   // imf1
        } else {
            out[2 * (size_t)TN + idx] = v.x * sgn;  // imf2
        }
    }
}

// ---------------------------------------------------------------------------
extern "C" void kernel_launch(void* const* d_in, const int* in_sizes, int n_in,
                              void* d_out, int out_size, void* d_ws, size_t ws_size,
                              hipStream_t stream) {
    (void)in_sizes; (void)n_in; (void)out_size;
    const float* x      = (const float*)d_in[0];
    const float* omega0 = (const float*)d_in[1];
    float* outp = (float*)d_out;
    char* ws = (char*)d_ws;

    const size_t MB = (size_t)1 << 20;
    const size_t KB = (size_t)1 << 10;
    float2* fhat = (float2*)(ws);                      // 8 MB (scrambled)
    float*  pB   = (float*)(ws + 8 * MB);              // 128 KB
    float*  pM   = (float*)(ws + 8 * MB + 128 * KB);   // 128 KB
    float*  sgsb = (float*)(ws + 8 * MB + 256 * KB);   // 8 KB
    float*  oomf = (float*)(ws + 8 * MB + 264 * KB);   // 3 floats
    const bool batch2 = ws_size >= 42 * MB;
    float2* sA = (float2*)(ws + 9 * MB);               // 16 or 8 MB
    float2* sB = batch2 ? (float2*)(ws + 25 * MB)
                        : (float2*)(ws + 17 * MB);

    dim3 tb(32, 8);
    dim3 tg(32, 32);

    // forward FFT of (-1)^n*x -> fhat in scrambled order (4 passes)
    k_tr_fwd_in<<<tg, tb, 0, stream>>>(x, sA);
    k_fft1024<<<1024, 256, 0, stream>>>(sA, sB, -1.0f, 1);
    k_tr_c2c<<<tg, tb, 0, stream>>>(sB, sA);
    k_fft1024<<<1024, 256, 0, stream>>>(sA, fhat, -1.0f, 0);

    // fused spectrum compression: fhat -> per-slab bin partials
    k_binpart<<<tg, tb, 0, stream>>>(fhat, pB, pM);

    // 49 omega updates in one small block
    k_omega<<<1, 256, 0, stream>>>(pB, pM, omega0, oomf, sgsb);

    // Hermitian-packed inverse: 2 complex iFFTs -> 3 real IMFs
    if (batch2) {
        k_fftu<<<2048, 256, 0, stream>>>(fhat, sgsb, oomf, sB, 0);
        k_tr_c2c<<<dim3(32, 32, 2), tb, 0, stream>>>(sB, sA);
        k_fft1024<<<2048, 256, 0, stream>>>(sA, sB, 1.0f, 0);
        k_tr_out<<<dim3(32, 32, 2), tb, 0, stream>>>(sB, outp, 0);
    } else {
        for (int z = 0; z < 2; ++z) {
            k_fftu<<<1024, 256, 0, stream>>>(fhat, sgsb, oomf, sB, z);
            k_tr_c2c<<<tg, tb, 0, stream>>>(sB, sA);
            k_fft1024<<<1024, 256, 0, stream>>>(sA, sB, 1.0f, 0);
            k_tr_out<<<dim3(32, 32, 1), tb, 0, stream>>>(sB, outp, z);
        }
    }
}

// Round 12
// 180.506 us; speedup vs baseline: 1.2101x; 1.0786x over previous
//
#include <hip/hip_runtime.h>
#include <math.h>

// ---------------------------------------------------------------------------
// VMD, T = 2^20, K = 3.  u[k][t] = (f_hat[t] - lam[t]/2) * g_k(t), g_k real.
// fftshift folded into (-1)^n input modulation; ifftshift into (-1)^n output.
//
// Round-12: k_omega is latency-bound at 1 wave/SIMD (59% VALU busy on its CU,
// ~1us/iter exposed stalls).  Two levers: 1024 bins (halves issue count;
// binning error (h/w)^2/12 ~ 1.6e-4 on sums -> ~5e-4 on output, >>margin) and
// 512 threads x 2 bins = 2 waves/SIMD (stall hiding).  Round-10's 512-thread
// regression was its 64-read LDS tail, which round 11 eliminated.
// Everything else unchanged (fused binpart, one-barrier readlane tail,
// Hermitian-packed 2-iFFT inverse).
// ---------------------------------------------------------------------------

#define TN        (1 << 20)
#define NBINS     1024
#define PPB       1024         // points per bin (TN/NBINS)
#define FALPHA    2000.0f
#define FTAU      1e-7f
#define FTOL      1e-6f
#define FEPS      1e-8f
#define FTWO_PI   6.28318530717958647692f
#define FINV_T    (1.0f / 1048576.0f)

__device__ __forceinline__ float2 cmulf(float2 a, float2 b) {
    return make_float2(a.x * b.x - a.y * b.y, a.x * b.y + a.y * b.x);
}
__device__ __forceinline__ float2 cisf(float a) {
    float s, c;
    __sincosf(a, &s, &c);
    return make_float2(c, s);
}
__device__ __forceinline__ float rlanef(float v, int l) {
    return __int_as_float(__builtin_amdgcn_readlane(__float_as_int(v), l));
}

// g_k(fr) for K=3 with neighbor coupling (stale omega, like the reference)
__device__ __forceinline__ void g3f(float fr, float om0, float om1, float om2,
                                    float& g0, float& g1, float& g2) {
    const float tau2 = FTAU * FTAU;
    float d0 = fr - om0; d0 *= d0;
    float d1 = fr - om1; d1 *= d1;
    float d2 = fr - om2; d2 *= d2;
    g0 = __builtin_amdgcn_rcpf(1.0f + FALPHA * (d0 + d1 + tau2));
    g1 = __builtin_amdgcn_rcpf(1.0f + FALPHA * (d0 + d1 + d2 + tau2));
    g2 = __builtin_amdgcn_rcpf(1.0f + FALPHA * (d1 + d2 + tau2));
}

// wave64 sum via DPP: result valid in lane 63.
__device__ __forceinline__ float dpp_wave_sum(float x) {
    x += __int_as_float(__builtin_amdgcn_update_dpp(
             0, __float_as_int(x), 0x111, 0xf, 0xf, true));  // row_shr:1
    x += __int_as_float(__builtin_amdgcn_update_dpp(
             0, __float_as_int(x), 0x112, 0xf, 0xf, true));  // row_shr:2
    x += __int_as_float(__builtin_amdgcn_update_dpp(
             0, __float_as_int(x), 0x114, 0xf, 0xf, true));  // row_shr:4
    x += __int_as_float(__builtin_amdgcn_update_dpp(
             0, __float_as_int(x), 0x118, 0xf, 0xf, true));  // row_shr:8
    x += __int_as_float(__builtin_amdgcn_update_dpp(
             0, __float_as_int(x), 0x142, 0xf, 0xf, true));  // row_bcast:15
    x += __int_as_float(__builtin_amdgcn_update_dpp(
             0, __float_as_int(x), 0x143, 0xf, 0xf, true));  // row_bcast:31
    return x;
}
// 32-lane sums: lane31 = sum(0..31), lane63 = sum(32..63).
__device__ __forceinline__ float dpp_sum32(float x) {
    x += __int_as_float(__builtin_amdgcn_update_dpp(
             0, __float_as_int(x), 0x111, 0xf, 0xf, true));
    x += __int_as_float(__builtin_amdgcn_update_dpp(
             0, __float_as_int(x), 0x112, 0xf, 0xf, true));
    x += __int_as_float(__builtin_amdgcn_update_dpp(
             0, __float_as_int(x), 0x114, 0xf, 0xf, true));
    x += __int_as_float(__builtin_amdgcn_update_dpp(
             0, __float_as_int(x), 0x118, 0xf, 0xf, true));
    x += __int_as_float(__builtin_amdgcn_update_dpp(
             0, __float_as_int(x), 0x142, 0xf, 0xf, true));  // row_bcast:15
    return x;
}

// ---------------------------------------------------------------------------
// fused |fhat|^2 + transpose + bin-partials.  True index of scrambled
// (qr,qc) is qc*1024+qr; tile[tx][ty+j] has r_true = bx+ty+j (= bin) and
// c_true = by+tx.  Each 32-lane half-wave sums one r_true over its 32-col
// slab.  Layout: pB[bin*32 + slab], slab = blockIdx.y.
// ---------------------------------------------------------------------------
__global__ __launch_bounds__(256)
void k_binpart(const float2* __restrict__ in, float* __restrict__ pB,
               float* __restrict__ pM) {
    __shared__ float tile[32][33];
    const int bx = blockIdx.x * 32, by = blockIdx.y * 32;
    const int tx = threadIdx.x, ty = threadIdx.y;
#pragma unroll
    for (int j = 0; j < 32; j += 8) {
        const float2 v = in[(size_t)(by + ty + j) * 1024 + bx + tx];
        tile[ty + j][tx] = v.x * v.x + v.y * v.y;
    }
    __syncthreads();
    const int sIdx = blockIdx.y;              // slab (which 32-col group)
    const float d = ((float)(by + tx) - 511.5f) * FINV_T;  // fr - bin center
    const int lane = (tx + 32 * ty) & 63;
#pragma unroll
    for (int j = 0; j < 32; j += 8) {
        float s = tile[tx][ty + j];           // m2 at (r_true=bx+ty+j, c_true=by+tx)
        float m = s * d;
        s = dpp_sum32(s);
        m = dpp_sum32(m);
        if (lane == 31 || lane == 63) {
            const int bin = bx + ty + j;      // = r_true
            pB[bin * 32 + sIdx] = s;
            pM[bin * 32 + sIdx] = m;
        }
    }
}

// ---------------------------------------------------------------------------
// 49 omega updates over 1024 bins: 512 threads x 2 bins (2 waves/SIMD).
// Per bin & k: P_k = g^2*B + (g^2)'*M1,  W_k = c*P_k + g^2*M1,
// (g^2)' = -4*alpha*Dp_k*g^3.  sgs accumulates sum_i(gs_i - 1).
// ---------------------------------------------------------------------------
__global__ __launch_bounds__(512)
void k_omega(const float* __restrict__ pB, const float* __restrict__ pM,
             const float* __restrict__ omega0,
             float* __restrict__ oomf, float* __restrict__ sgsb) {
    const int tid = threadIdx.x;
    const int lane = tid & 63, wid = tid >> 6;   // 8 waves
    const float kA = -4.0f * FALPHA;

    float B[2], M[2], C[2], SG[2], gp[2];
#pragma unroll
    for (int i = 0; i < 2; ++i) {
        const int j = tid + 512 * i;
        float sb = 0.f, sm = 0.f;
#pragma unroll
        for (int s = 0; s < 32; ++s) {        // fixed order -> deterministic
            sb += pB[j * 32 + s];
            sm += pM[j * 32 + s];
        }
        B[i] = sb; M[i] = sm;
        C[i] = ((float)(j * PPB) + 511.5f) * FINV_T - 0.5f;
        SG[i] = 0.f; gp[i] = 0.f;
    }

    float om0 = 0.5f * omega0[0];
    float om1 = 0.5f * omega0[1];
    float om2 = 0.5f * omega0[2];
    float op0 = om0, op1 = om1, op2 = om2;
    float n0 = om0, n1 = om1, n2 = om2;
    float stop = 0.f;

    __shared__ float wsum[2][8][8];           // parity double-buffer
    bool fin = true;

    for (int n = 0; n < 49; ++n) {
        if (n > 0) {
            if (stop != 0.f) { fin = false; break; }
            op0 = om0; op1 = om1; op2 = om2;
            om0 = n0; om1 = n1; om2 = n2;
#pragma unroll
            for (int i = 0; i < 2; ++i) SG[i] += gp[i] - 1.0f;  // gs_{n-1}
        }
        const int check = (n > 0 && n % 10 == 0);

        float a[8];
#pragma unroll
        for (int v = 0; v < 8; ++v) a[v] = 0.f;

#pragma unroll
        for (int i = 0; i < 2; ++i) {
            const float c  = C[i];
            const float Bv = B[i];
            const float M1 = M[i];
            const float e0 = c - om0, e1 = c - om1, e2 = c - om2;
            float g0, g1, g2;
            g3f(c, om0, om1, om2, g0, g1, g2);
            const float gsq0 = g0 * g0, gsq1 = g1 * g1, gsq2 = g2 * g2;
            const float gc0 = gsq0 * g0, gc1 = gsq1 * g1, gc2 = gsq2 * g2;
            const float Dp0 = e0 + e1, Dp1 = e0 + e1 + e2, Dp2 = e1 + e2;
            const float P0 = gsq0 * Bv + kA * Dp0 * gc0 * M1;
            const float P1 = gsq1 * Bv + kA * Dp1 * gc1 * M1;
            const float P2 = gsq2 * Bv + kA * Dp2 * gc2 * M1;
            a[0] += P0; a[1] += P1; a[2] += P2;
            a[3] += c * P0 + gsq0 * M1;
            a[4] += c * P1 + gsq1 * M1;
            a[5] += c * P2 + gsq2 * M1;
            gp[i] = g0 + g1 + g2;
            if (check) {
                float h0, h1, h2;
                g3f(c, op0, op1, op2, h0, h1, h2);
                const float d0 = g0 - h0, d1 = g1 - h1, d2 = g2 - h2;
                a[6] += Bv * (d0 * d0 + d1 * d1 + d2 * d2);
                a[7] += Bv * (h0 * h0 + h1 * h1 + h2 * h2);
            }
        }
        // wave sums land in lane 63; 2 float4 LDS stores from that lane
#pragma unroll
        for (int v = 0; v < 8; ++v) a[v] = dpp_wave_sum(a[v]);
        if (lane == 63) {
            *(float4*)&wsum[n & 1][wid][0] = make_float4(a[0], a[1], a[2], a[3]);
            *(float4*)&wsum[n & 1][wid][4] = make_float4(a[4], a[5], a[6], a[7]);
        }
        __syncthreads();                       // the ONLY barrier per iter
        // every lane: 8 broadcast reads -> lane l holds S[l&7]; readlane ->
        // uniform totals, identical in every wave (same data, same order).
        float r = 0.f;
#pragma unroll
        for (int w = 0; w < 8; ++w) r += wsum[n & 1][w][lane & 7];
        const float S0 = rlanef(r, 0), S1 = rlanef(r, 1), S2 = rlanef(r, 2);
        const float S3 = rlanef(r, 3), S4 = rlanef(r, 4), S5 = rlanef(r, 5);
        n0 = S3 * __builtin_amdgcn_rcpf(S0 + FEPS);
        n1 = S4 * __builtin_amdgcn_rcpf(S1 + FEPS);
        n2 = S5 * __builtin_amdgcn_rcpf(S2 + FEPS);
        if (check) {
            const float S6 = rlanef(r, 6), S7 = rlanef(r, 7);
            const float ud = S6 * __builtin_amdgcn_rcpf(S7 + FEPS);
            const float od = (fabsf(n0 - n2) + fabsf(n1 - n0) +
                              fabsf(n2 - n1)) * (1.0f / 3.0f);
            stop = (ud < FTOL && od < FTOL) ? 1.f : 0.f;
        }
    }

    if (fin) {             // completed: omega entering iter 49, sgs 0..48
#pragma unroll
        for (int i = 0; i < 2; ++i) SG[i] += gp[i] - 1.0f;
        om0 = n0; om1 = n1; om2 = n2;
    }
#pragma unroll
    for (int i = 0; i < 2; ++i) sgsb[tid + 512 * i] = SG[i];
    if (tid == 0) { oomf[0] = om0; oomf[1] = om1; oomf[2] = om2; }
}

// ---------------------------------------------------------------------------
// 1024-point Stockham radix-4 stages in LDS (caller loads bufA, then syncs)
// ---------------------------------------------------------------------------
__device__ __forceinline__ float2* fft1024_stages(float2* bufA, float2* bufB,
                                                  int t, float dir) {
    float2* src = bufA;
    float2* dst = bufB;
    int Ns = 1;
#pragma unroll
    for (int s = 0; s < 5; ++s) {
        const int jm = t & (Ns - 1);
        float2 v0 = src[t], v1 = src[t + 256], v2 = src[t + 512], v3 = src[t + 768];
        const float a = dir * (FTWO_PI * 0.25f) * ((float)jm / (float)Ns);
        float2 w1 = cisf(a);
        float2 w2 = cmulf(w1, w1);
        float2 w3 = cmulf(w2, w1);
        v1 = cmulf(v1, w1); v2 = cmulf(v2, w2); v3 = cmulf(v3, w3);
        float2 s0 = make_float2(v0.x + v2.x, v0.y + v2.y);
        float2 s1 = make_float2(v0.x - v2.x, v0.y - v2.y);
        float2 s2 = make_float2(v1.x + v3.x, v1.y + v3.y);
        float2 s3 = make_float2(v1.x - v3.x, v1.y - v3.y);
        float2 s3i = make_float2(-dir * s3.y, dir * s3.x);  // dir*i * s3
        const int base = ((t - jm) << 2) + jm;
        dst[base]          = make_float2(s0.x + s2.x, s0.y + s2.y);
        dst[base + Ns]     = make_float2(s1.x + s3i.x, s1.y + s3i.y);
        dst[base + 2 * Ns] = make_float2(s0.x - s2.x, s0.y - s2.y);
        dst[base + 3 * Ns] = make_float2(s1.x - s3i.x, s1.y - s3i.y);
        __syncthreads();
        float2* tmp = src; src = dst; dst = tmp;
        Ns <<= 2;
    }
    return src;
}

// generic row FFT: dir=-1 fwd / +1 inv; do_tw: * e^{dir*2pi*i*row*col/2^20}
__global__ __launch_bounds__(256)
void k_fft1024(const float2* __restrict__ in, float2* __restrict__ out,
               float dir, int do_tw) {
    __shared__ float2 bufA[1024];
    __shared__ float2 bufB[1024];
    const int row  = blockIdx.x;
    const int rowm = row & 1023;
    const float2* __restrict__ rin  = in  + (size_t)row * 1024;
    float2* __restrict__ rout = out + (size_t)row * 1024;
    const int t = threadIdx.x;
#pragma unroll
    for (int r = 0; r < 4; ++r) bufA[t + 256 * r] = rin[t + 256 * r];
    __syncthreads();
    float2* src = fft1024_stages(bufA, bufB, t, dir);
#pragma unroll
    for (int r = 0; r < 4; ++r) {
        const int c = t + 256 * r;
        float2 xv = src[c];
        if (do_tw) {
            const unsigned p = ((unsigned)rowm * (unsigned)c) & 1048575u;
            xv = cmulf(xv, cisf(dir * (FTWO_PI * FINV_T) * (float)p));
        }
        rout[c] = xv;
    }
}

// first inverse-FFT pass, Hermitian-packed filters fused into the load:
// z=0: Z = fhat*(Rsym_0 + i*Rsym_1)  (ifft -> imf0 + i*imf1, both real)
// z=1: Z = fhat*Rsym_2               (ifft real part -> imf2)
// Rsym_k(t) = (g_k(fr)*sc(t) + g_k(fr_m)*sc(tm))/2, tm = (N-t)&(N-1).
__global__ __launch_bounds__(256)
void k_fftu(const float2* __restrict__ fhat, const float* __restrict__ sgsb,
            const float* __restrict__ oomf,
            float2* __restrict__ out, int zbase) {
    __shared__ float2 bufA[1024];
    __shared__ float2 bufB[1024];
    const int row = blockIdx.x & 1023;
    const int zi  = blockIdx.x >> 10;
    const int z   = zi + zbase;
    const float om0 = oomf[0], om1 = oomf[1], om2 = oomf[2];
    const float2* __restrict__ frow = fhat + (size_t)row * 1024;
    const int t = threadIdx.x;
#pragma unroll
    for (int r = 0; r < 4; ++r) {
        const int c = t + 256 * r;
        const float2 f = frow[c];
        const int tt = (c << 10) | row;
        const float fr = (float)tt * FINV_T - 0.5f;
        const float sc = 1.0f - 0.5f * FTAU * sgsb[tt >> 10];
        float g0, g1, g2;
        g3f(fr, om0, om1, om2, g0, g1, g2);
        const int tm = (TN - tt) & (TN - 1);
        const float frm = (float)tm * FINV_T - 0.5f;
        const float scm = 1.0f - 0.5f * FTAU * sgsb[tm >> 10];
        float h0, h1, h2;
        g3f(frm, om0, om1, om2, h0, h1, h2);
        float A, Bi;
        if (z == 0) {
            A  = 0.5f * (g0 * sc + h0 * scm);
            Bi = 0.5f * (g1 * sc + h1 * scm);
        } else {
            A  = 0.5f * (g2 * sc + h2 * scm);
            Bi = 0.f;
        }
        bufA[c] = cmulf(f, make_float2(A, Bi));
    }
    __syncthreads();
    float2* src = fft1024_stages(bufA, bufB, t, 1.0f);
    float2* __restrict__ rout = out + (size_t)zi * TN + (size_t)row * 1024;
#pragma unroll
    for (int r = 0; r < 4; ++r) {
        const int c = t + 256 * r;
        const unsigned p = ((unsigned)row * (unsigned)c) & 1048575u;
        rout[c] = cmulf(src[c], cisf((FTWO_PI * FINV_T) * (float)p));
    }
}

// ---------------------------------------------------------------------------
// transposes (32x32 LDS tiles, block (32,8)); grid z = batch
// ---------------------------------------------------------------------------
__global__ __launch_bounds__(256)
void k_tr_c2c(const float2* __restrict__ in, float2* __restrict__ out) {
    __shared__ float2 tile[32][33];
    const size_t zo = (size_t)blockIdx.z * TN;
    const int bx = blockIdx.x * 32, by = blockIdx.y * 32;
    const int tx = threadIdx.x, ty = threadIdx.y;
#pragma unroll
    for (int j = 0; j < 32; j += 8)
        tile[ty + j][tx] = in[zo + (size_t)(by + ty + j) * 1024 + bx + tx];
    __syncthreads();
#pragma unroll
    for (int j = 0; j < 32; j += 8)
        out[zo + (size_t)(bx + ty + j) * 1024 + by + tx] = tile[tx][ty + j];
}

// forward input: y = (-1)^n * x, transposed, real -> complex
__global__ __launch_bounds__(256)
void k_tr_fwd_in(const float* __restrict__ in, float2* __restrict__ out) {
    __shared__ float tile[32][33];
    const int bx = blockIdx.x * 32, by = blockIdx.y * 32;
    const int tx = threadIdx.x, ty = threadIdx.y;
#pragma unroll
    for (int j = 0; j < 32; j += 8)
        tile[ty + j][tx] = in[(size_t)(by + ty + j) * 1024 + bx + tx];
    __syncthreads();
#pragma unroll
    for (int j = 0; j < 32; j += 8) {
        const int r = bx + ty + j;
        float v = tile[tx][ty + j];
        v = (r & 1) ? -v : v;
        out[(size_t)r * 1024 + by + tx] = make_float2(v, 0.0f);
    }
}

// inverse output: imf = (-1)^n * (1/N) * (re, and im if packed), transposed.
// z==0 block writes imf0 (re) and imf1 (im); z==1 writes imf2 (re).
__global__ __launch_bounds__(256)
void k_tr_out(const float2* __restrict__ in, float* __restrict__ out,
              int zbase) {
    __shared__ float2 tile[32][33];
    const int z = blockIdx.z + zbase;
    const size_t zo = (size_t)blockIdx.z * TN;
    const int bx = blockIdx.x * 32, by = blockIdx.y * 32;
    const int tx = threadIdx.x, ty = threadIdx.y;
#pragma unroll
    for (int j = 0; j < 32; j += 8)
        tile[ty + j][tx] = in[zo + (size_t)(by + ty + j) * 1024 + bx + tx];
    __syncthreads();
    const int c = by + tx;
    const float sgn = (c & 1) ? -FINV_T : FINV_T;
#pragma unroll
    for (int j = 0; j < 32; j += 8) {
        const int r = bx + ty + j;
        const float2 v = tile[tx][ty + j];
        const size_t idx = (size_t)r * 1024 + c;
        if (z == 0) {
            out[idx]              = v.x * sgn;   // imf0
            out[(size_t)TN + idx] = v.y * sgn;   // imf1
        } else {
            out[2 * (size_t)TN + idx] = v.x * sgn;  // imf2
        }
    }
}

// ---------------------------------------------------------------------------
extern "C" void kernel_launch(void* const* d_in, const int* in_sizes, int n_in,
                              void* d_out, int out_size, void* d_ws, size_t ws_size,
                              hipStream_t stream) {
    (void)in_sizes; (void)n_in; (void)out_size;
    const float* x      = (const float*)d_in[0];
    const float* omega0 = (const float*)d_in[1];
    float* outp = (float*)d_out;
    char* ws = (char*)d_ws;

    const size_t MB = (size_t)1 << 20;
    const size_t KB = (size_t)1 << 10;
    float2* fhat = (float2*)(ws);                      // 8 MB (scrambled)
    float*  pB   = (float*)(ws + 8 * MB);              // 128 KB
    float*  pM   = (float*)(ws + 8 * MB + 128 * KB);   // 128 KB
    float*  sgsb = (float*)(ws + 8 * MB + 256 * KB);   // 4 KB
    float*  oomf = (float*)(ws + 8 * MB + 264 * KB);   // 3 floats
    const bool batch2 = ws_size >= 42 * MB;
    float2* sA = (float2*)(ws + 9 * MB);               // 16 or 8 MB
    float2* sB = batch2 ? (float2*)(ws + 25 * MB)
                        : (float2*)(ws + 17 * MB);

    dim3 tb(32, 8);
    dim3 tg(32, 32);

    // forward FFT of (-1)^n*x -> fhat in scrambled order (4 passes)
    k_tr_fwd_in<<<tg, tb, 0, stream>>>(x, sA);
    k_fft1024<<<1024, 256, 0, stream>>>(sA, sB, -1.0f, 1);
    k_tr_c2c<<<tg, tb, 0, stream>>>(sB, sA);
    k_fft1024<<<1024, 256, 0, stream>>>(sA, fhat, -1.0f, 0);

    // fused spectrum compression: fhat -> per-slab bin partials
    k_binpart<<<tg, tb, 0, stream>>>(fhat, pB, pM);

    // 49 omega updates in one small block
    k_omega<<<1, 512, 0, stream>>>(pB, pM, omega0, oomf, sgsb);

    // Hermitian-packed inverse: 2 complex iFFTs -> 3 real IMFs
    if (batch2) {
        k_fftu<<<2048, 256, 0, stream>>>(fhat, sgsb, oomf, sB, 0);
        k_tr_c2c<<<dim3(32, 32, 2), tb, 0, stream>>>(sB, sA);
        k_fft1024<<<2048, 256, 0, stream>>>(sA, sB, 1.0f, 0);
        k_tr_out<<<dim3(32, 32, 2), tb, 0, stream>>>(sB, outp, 0);
    } else {
        for (int z = 0; z < 2; ++z) {
            k_fftu<<<1024, 256, 0, stream>>>(fhat, sgsb, oomf, sB, z);
            k_tr_c2c<<<tg, tb, 0, stream>>>(sB, sA);
            k_fft1024<<<1024, 256, 0, stream>>>(sA, sB, 1.0f, 0);
            k_tr_out<<<dim3(32, 32, 1), tb, 0, stream>>>(sB, outp, z);
        }
    }
}